// Round 5
// baseline (354.520 us; speedup 1.0000x reference)
//
#include <hip/hip_runtime.h>
#include <hip/hip_bf16.h>
#include <cstdint>
#include <cstddef>

// MHA B=2,S=2048,D=1024,H=16,HD=64.
// cvt -> QKV GEMM (m97 async staging; K written FRAGMENT-MAJOR in epilogue) ->
// vpack (V -> fragment-major, one-time) -> flash attn (coalesced direct-global
// K/V frags, LDS only for P) -> O GEMM.
//
// R3 lesson: cross-lane LDS write->read must be barrier-bracketed.
// R4 lesson: direct-global MFMA fragments need a CONTIGUOUS lane->address map;
//   divergent 16-row gathers in the hot loop cost ~16x VMEM transactions.
//   Fix: pre-pack K/V so each fragment is one coalesced 1KB wave load.

#define B_  2
#define S_  2048
#define D_  1024
#define H_  16
#define HD_ 64

typedef __bf16 bf16x8 __attribute__((ext_vector_type(8)));
typedef __bf16 bf16x4 __attribute__((ext_vector_type(4)));
typedef float  f32x4  __attribute__((ext_vector_type(4)));

// ---- async global->LDS, 16B per lane (wave-uniform LDS base + lane*16).
__device__ __forceinline__ void async16(const __bf16* g, const __bf16* l) {
  __builtin_amdgcn_global_load_lds(
      (const __attribute__((address_space(1))) void*)(uintptr_t)g,
      (__attribute__((address_space(3))) void*)(uint32_t)(uintptr_t)l,
      16, 0, 0);
}

// ---------------- fp32 -> bf16 convert (x + 4 weights) ----------------
__global__ __launch_bounds__(256) void cvt_all(const float* __restrict__ x,
    const float* __restrict__ wq, const float* __restrict__ wk,
    const float* __restrict__ wv, const float* __restrict__ wo,
    __bf16* __restrict__ xb, __bf16* __restrict__ wqb, __bf16* __restrict__ wkb,
    __bf16* __restrict__ wvb, __bf16* __restrict__ wob) {
  const int sel = blockIdx.y;
  const float* src; __bf16* dst; int n;
  if      (sel == 0) { src = x;  dst = xb;  n = B_ * S_ * D_; }
  else if (sel == 1) { src = wq; dst = wqb; n = D_ * D_; }
  else if (sel == 2) { src = wk; dst = wkb; n = D_ * D_; }
  else if (sel == 3) { src = wv; dst = wvb; n = D_ * D_; }
  else               { src = wo; dst = wob; n = D_ * D_; }
  for (int i = blockIdx.x * 256 + threadIdx.x; i * 4 < n; i += gridDim.x * 256) {
    const float4 v = *(const float4*)(src + (size_t)i * 4);
    bf16x4 o;
    o[0] = (__bf16)v.x; o[1] = (__bf16)v.y; o[2] = (__bf16)v.z; o[3] = (__bf16)v.w;
    *(bf16x4*)(dst + (size_t)i * 4) = o;
  }
}

// ---------------- m97-style GEMM body with pluggable store ----------------
template <typename F>
__device__ __forceinline__ void gemm97_body(const __bf16* __restrict__ A,
                                            const __bf16* __restrict__ Bm,
                                            const int m0, const int n0,
                                            const int K, F&& store) {
  __shared__ __align__(16) __bf16 As[128 * 64];
  __shared__ __align__(16) __bf16 Bs[128 * 64];
  const int tid  = threadIdx.x, lane = tid & 63, wave = tid >> 6;
  const int l15  = lane & 15,   quad = lane >> 4;
  const int wr   = wave >> 1,   wc   = wave & 1;
  const int ebase = wave * 2048 + lane * 8;

  f32x4 acc[4][4] = {};
  for (int k0 = 0; k0 < K; k0 += 64) {
#pragma unroll
    for (int i = 0; i < 4; ++i) {
      const int e = ebase + i * 512;
      const int row = e >> 6, col = e & 63;
      async16(A  + (size_t)(m0 + row) * K + k0 + col, As + (wave * 4 + i) * 512);
      async16(Bm + (size_t)(n0 + row) * K + k0 + col, Bs + (wave * 4 + i) * 512);
    }
    __syncthreads();
#pragma unroll
    for (int kk = 0; kk < 2; ++kk) {
      bf16x8 af[4], bfv[4];
#pragma unroll
      for (int rt = 0; rt < 4; ++rt)
        af[rt] = *(const bf16x8*)(As + (wr * 64 + rt * 16 + l15) * 64 + kk * 32 + quad * 8);
#pragma unroll
      for (int ct = 0; ct < 4; ++ct)
        bfv[ct] = *(const bf16x8*)(Bs + (wc * 64 + ct * 16 + l15) * 64 + kk * 32 + quad * 8);
#pragma unroll
      for (int rt = 0; rt < 4; ++rt)
#pragma unroll
        for (int ct = 0; ct < 4; ++ct)
          acc[rt][ct] = __builtin_amdgcn_mfma_f32_16x16x32_bf16(af[rt], bfv[ct], acc[rt][ct], 0, 0, 0);
    }
    __syncthreads();
  }
#pragma unroll
  for (int rt = 0; rt < 4; ++rt)
#pragma unroll
    for (int ct = 0; ct < 4; ++ct)
#pragma unroll
      for (int r = 0; r < 4; ++r) {
        const int row = m0 + wr * 64 + rt * 16 + quad * 4 + r;
        const int col = n0 + wc * 64 + ct * 16 + l15;
        store(row, col, acc[rt][ct][r]);
      }
}

// Q,V row-major; K written fragment-major:
// Kf[bh][T][kti][kk][lane][j] = K[s = T*128+kti*16+(lane&15)][d = h*64+kk*32+(lane>>4)*8+j]
__global__ __launch_bounds__(256) void qkv_gemm(const __bf16* __restrict__ xb,
                                                const __bf16* __restrict__ wq,
                                                const __bf16* __restrict__ wk,
                                                const __bf16* __restrict__ wv,
                                                __bf16* __restrict__ qb,
                                                __bf16* __restrict__ kfb,
                                                __bf16* __restrict__ vb) {
  const int sel = blockIdx.x >> 3;
  const int m0 = blockIdx.y * 128, n0 = (blockIdx.x & 7) * 128;
  if (sel == 1) {
    gemm97_body(xb, wk, m0, n0, D_, [&](int row, int col, float v) {
      const int b = row >> 11, ss = row & 2047;
      const int T = ss >> 7, kti = (ss >> 4) & 7, l15k = ss & 15;
      const int h = col >> 6, dd = col & 63;
      const int kk = dd >> 5, quadk = (dd >> 3) & 3, j = dd & 7;
      kfb[((size_t)((b * 16 + h) * 16 + T)) * 8192 +
          ((kti * 2 + kk) * 64 + l15k + quadk * 16) * 8 + j] = (__bf16)v;
    });
  } else {
    __bf16* C = (sel == 0) ? qb : vb;
    const __bf16* Bm = (sel == 0) ? wq : wv;
    gemm97_body(xb, Bm, m0, n0, D_, [&](int row, int col, float v) {
      C[(size_t)row * D_ + col] = (__bf16)v;
    });
  }
}

__global__ __launch_bounds__(256) void o_gemm(const __bf16* __restrict__ cb,
                                              const __bf16* __restrict__ wo,
                                              float* __restrict__ out) {
  gemm97_body(cb, wo, blockIdx.y * 128, blockIdx.x * 128, D_,
              [&](int row, int col, float v) { out[(size_t)row * D_ + col] = v; });
}

// ---------------- V -> fragment-major pack (one-time) ----------------
// Vf[bh][T][nt][kb][lane][j] = V[s = T*128+kb*32+(lane>>4)*8+j][d = h*64+nt*16+(lane&15)]
__global__ __launch_bounds__(256) void vpack(const __bf16* __restrict__ vb,
                                             __bf16* __restrict__ Vf) {
  __shared__ __bf16 tb[128][72];
  const int tid = threadIdx.x;
  const int T = blockIdx.x, bh = blockIdx.y;
  const int b = bh >> 4, h = bh & 15;
  const __bf16* src = vb + ((size_t)b * S_ + T * 128) * D_ + h * HD_;
#pragma unroll
  for (int i = 0; i < 4; ++i) {
    const int c = tid + i * 256;
    const int r = c >> 3, ch = (c & 7) * 8;
    *(bf16x8*)(&tb[r][ch]) = *(const bf16x8*)(src + (size_t)r * D_ + ch);
  }
  __syncthreads();
  __bf16* dst = Vf + ((size_t)bh * 16 + T) * 8192;
#pragma unroll
  for (int i = 0; i < 4; ++i) {
    const int c = tid + i * 256;
    const int nt = c >> 8, kb2 = (c >> 6) & 3, lane = c & 63;
    const int hd = nt * 16 + (lane & 15);
    const int k0 = kb2 * 32 + (lane >> 4) * 8;
    bf16x8 v;
#pragma unroll
    for (int j = 0; j < 8; ++j) v[j] = tb[k0 + j][hd];
    *(bf16x8*)(dst + (size_t)c * 8) = v;
  }
}

// ---------------- flash attention: coalesced frag-major K/V ----------------
// Block: 128 q of one (b,h); 4 waves x 32 q. Every in-loop K/V fragment load is
// one coalesced 1KB wave load (lane-indexed). LDS = ps only; write->read
// barrier-bracketed (R3). 34.8 KB LDS + <=128 VGPR -> 4 blocks/CU.
__global__ __launch_bounds__(256, 4) void attn5(const __bf16* __restrict__ Q,
                                                const __bf16* __restrict__ Kf,
                                                const __bf16* __restrict__ Vf,
                                                const float* __restrict__ mask,
                                                __bf16* __restrict__ O) {
  constexpr int LPS = 136;
  __shared__ __align__(16) __bf16 ps[128 * LPS];

  const int tid  = threadIdx.x, lane = tid & 63, wave = tid >> 6;
  const int l15  = lane & 15,   quad = lane >> 4;
  const int b = blockIdx.z, h = blockIdx.y, q0 = blockIdx.x * 128;
  const int bh = b * H_ + h;
  const size_t base = (size_t)b * S_ * D_ + h * HD_;
  const __bf16* kfh = Kf + (size_t)bh * (16 * 8192);
  const __bf16* vfh = Vf + (size_t)bh * (16 * 8192);
  const float* mrow = mask + (size_t)b * S_;
  const int qw = q0 + wave * 32;
  const float L2E = 1.442695041f;

  // Q fragments (B-operand; once per block)
  bf16x8 qf[2][2];
#pragma unroll
  for (int t = 0; t < 2; ++t)
#pragma unroll
    for (int kb = 0; kb < 2; ++kb)
      qf[t][kb] = *(const bf16x8*)(Q + base + (size_t)(qw + t * 16 + l15) * D_ + kb * 32 + quad * 8);

  float m_run[2] = {-1e30f, -1e30f}, l_run[2] = {0.f, 0.f};
  f32x4 oacc[2][4] = {};

  for (int T = 0; T < 16; ++T) {
    __syncthreads();  // prev iter's ps reads done before this iter's writes
    const __bf16* kft = kfh + (size_t)T * 8192;
    const __bf16* vft = vfh + (size_t)T * 8192;
    const int t0 = T * 128;

    // ---- S^T: D[m=key][n=q]; A-frags = coalesced lane-indexed loads ----
    f32x4 sacc[8][2] = {};
#pragma unroll
    for (int kti = 0; kti < 8; ++kti) {
      const bf16x8 a0 = *(const bf16x8*)(kft + (kti * 2 + 0) * 512 + lane * 8);
      const bf16x8 a1 = *(const bf16x8*)(kft + (kti * 2 + 1) * 512 + lane * 8);
#pragma unroll
      for (int t = 0; t < 2; ++t) {
        sacc[kti][t] = __builtin_amdgcn_mfma_f32_16x16x32_bf16(a0, qf[t][0], sacc[kti][t], 0, 0, 0);
        sacc[kti][t] = __builtin_amdgcn_mfma_f32_16x16x32_bf16(a1, qf[t][1], sacc[kti][t], 0, 0, 0);
      }
    }
    // scale + additive mask
#pragma unroll
    for (int kti = 0; kti < 8; ++kti) {
      const f32x4 mv = *(const f32x4*)(mrow + t0 + kti * 16 + quad * 4);
#pragma unroll
      for (int t = 0; t < 2; ++t)
#pragma unroll
        for (int r = 0; r < 4; ++r)
          sacc[kti][t][r] = fmaf(sacc[kti][t][r], 0.125f, mv[r]);
    }
    // online softmax
    float mnew[2], alpha[2], tsum[2], ml2[2];
#pragma unroll
    for (int t = 0; t < 2; ++t) {
      float tm = -1e30f;
#pragma unroll
      for (int kti = 0; kti < 8; ++kti)
#pragma unroll
        for (int r = 0; r < 4; ++r) tm = fmaxf(tm, sacc[kti][t][r]);
      tm = fmaxf(tm, __shfl_xor(tm, 16));
      tm = fmaxf(tm, __shfl_xor(tm, 32));
      mnew[t]  = fmaxf(m_run[t], tm);
      alpha[t] = __builtin_amdgcn_exp2f((m_run[t] - mnew[t]) * L2E);
      m_run[t] = mnew[t];
      ml2[t]   = mnew[t] * L2E;
      tsum[t]  = 0.f;
    }
    // P = exp2(...), write P[q][key]
#pragma unroll
    for (int t = 0; t < 2; ++t) {
      __bf16* pr = ps + (size_t)(wave * 32 + t * 16 + l15) * LPS + quad * 4;
#pragma unroll
      for (int kti = 0; kti < 8; ++kti) {
        bf16x4 pv;
#pragma unroll
        for (int r = 0; r < 4; ++r) {
          const float p = __builtin_amdgcn_exp2f(fmaf(sacc[kti][t][r], L2E, -ml2[t]));
          tsum[t] += p;
          pv[r] = (__bf16)p;
        }
        *(bf16x4*)(pr + kti * 16) = pv;
      }
    }
#pragma unroll
    for (int t = 0; t < 2; ++t) {
      float ts = tsum[t];
      ts += __shfl_xor(ts, 16);
      ts += __shfl_xor(ts, 32);
      l_run[t] = l_run[t] * alpha[t] + ts;
#pragma unroll
      for (int r = 0; r < 4; ++r) {
        const float aR = __shfl(alpha[t], quad * 4 + r);
#pragma unroll
        for (int nt = 0; nt < 4; ++nt) oacc[t][nt][r] *= aR;
      }
    }
    __syncthreads();  // ps writes before A-layout reads
    // ---- O += P·V; B-frags = coalesced lane-indexed loads ----
#pragma unroll
    for (int kb = 0; kb < 4; ++kb) {
      bf16x8 pa[2];
#pragma unroll
      for (int t = 0; t < 2; ++t)
        pa[t] = *(const bf16x8*)(ps + (size_t)(wave * 32 + t * 16 + l15) * LPS + kb * 32 + quad * 8);
#pragma unroll
      for (int nt = 0; nt < 4; ++nt) {
        const bf16x8 vf = *(const bf16x8*)(vft + (nt * 4 + kb) * 512 + lane * 8);
#pragma unroll
        for (int t = 0; t < 2; ++t)
          oacc[t][nt] = __builtin_amdgcn_mfma_f32_16x16x32_bf16(pa[t], vf, oacc[t][nt], 0, 0, 0);
      }
    }
  }
  // epilogue
#pragma unroll
  for (int t = 0; t < 2; ++t)
#pragma unroll
    for (int r = 0; r < 4; ++r) {
      const float lR  = __shfl(l_run[t], quad * 4 + r);
      const float inv = 1.0f / lR;
      const int row = qw + t * 16 + quad * 4 + r;
#pragma unroll
      for (int nt = 0; nt < 4; ++nt)
        O[base + (size_t)row * D_ + nt * 16 + l15] = (__bf16)(oacc[t][nt][r] * inv);
    }
}

extern "C" void kernel_launch(void* const* d_in, const int* in_sizes, int n_in,
                              void* d_out, int out_size, void* d_ws, size_t ws_size,
                              hipStream_t stream) {
  const float* x    = (const float*)d_in[0];
  const float* mask = (const float*)d_in[1];
  const float* Wq   = (const float*)d_in[2];
  const float* Wk   = (const float*)d_in[3];
  const float* Wv   = (const float*)d_in[4];
  const float* Wo   = (const float*)d_in[5];

  char* ws = (char*)d_ws;
  const size_t MB = 1ull << 20;
  __bf16* xb  = (__bf16*)(ws);             // 8 MB; reused as Vf after qkv_gemm
  __bf16* wqb = (__bf16*)(ws + 8 * MB);
  __bf16* wkb = (__bf16*)(ws + 10 * MB);
  __bf16* wvb = (__bf16*)(ws + 12 * MB);
  __bf16* wob = (__bf16*)(ws + 14 * MB);
  __bf16* qb  = (__bf16*)(ws + 16 * MB);   // 8 MB row-major Q
  __bf16* kfb = (__bf16*)(ws + 24 * MB);   // 8 MB fragment-major K
  __bf16* vb  = (__bf16*)(ws + 32 * MB);   // 8 MB row-major V
  __bf16* Vf  = xb;  // x consumed by qkv_gemm before vpack writes
  __bf16* cb  = vb;  // v consumed by vpack before attn writes ctx

  cvt_all<<<dim3(1024, 5), 256, 0, stream>>>(x, Wq, Wk, Wv, Wo, xb, wqb, wkb, wvb, wob);
  qkv_gemm<<<dim3(24, 32), 256, 0, stream>>>(xb, wqb, wkb, wvb, qb, kfb, vb);
  vpack<<<dim3(16, 32), 256, 0, stream>>>(vb, Vf);
  attn5<<<dim3(S_ / 128, H_, B_), 256, 0, stream>>>(qb, kfb, Vf, mask, cb);
  o_gemm<<<dim3(8, 32), 256, 0, stream>>>(cb, wob, (float*)d_out);
}

// Round 6
// 282.785 us; speedup vs baseline: 1.2537x; 1.2537x over previous
//
#include <hip/hip_runtime.h>
#include <hip/hip_bf16.h>
#include <cstdint>
#include <cstddef>

// MHA B=2,S=2048,D=1024,H=16,HD=64.
// cvt -> QKV GEMM (m97 async staging; K AND V written FRAGMENT-MAJOR in the
// epilogue) -> flash attn (coalesced direct-global K/V frags, LDS only for P)
// -> O GEMM.
//
// R3 lesson: cross-lane LDS write->read must be barrier-bracketed.
// R4 lesson: direct-global MFMA fragments need a CONTIGUOUS lane->address map.
// R5 lesson: do NOT add __launch_bounds__ min-waves on a register-heavy kernel;
//   (256,4) capped VGPRs and spilled sacc/oacc -> 217 MB scratch writes.

#define B_  2
#define S_  2048
#define D_  1024
#define H_  16
#define HD_ 64

typedef __bf16 bf16x8 __attribute__((ext_vector_type(8)));
typedef __bf16 bf16x4 __attribute__((ext_vector_type(4)));
typedef float  f32x4  __attribute__((ext_vector_type(4)));

// ---- async global->LDS, 16B per lane (wave-uniform LDS base + lane*16).
__device__ __forceinline__ void async16(const __bf16* g, const __bf16* l) {
  __builtin_amdgcn_global_load_lds(
      (const __attribute__((address_space(1))) void*)(uintptr_t)g,
      (__attribute__((address_space(3))) void*)(uint32_t)(uintptr_t)l,
      16, 0, 0);
}

// ---------------- fp32 -> bf16 convert (x + 4 weights) ----------------
__global__ __launch_bounds__(256) void cvt_all(const float* __restrict__ x,
    const float* __restrict__ wq, const float* __restrict__ wk,
    const float* __restrict__ wv, const float* __restrict__ wo,
    __bf16* __restrict__ xb, __bf16* __restrict__ wqb, __bf16* __restrict__ wkb,
    __bf16* __restrict__ wvb, __bf16* __restrict__ wob) {
  const int sel = blockIdx.y;
  const float* src; __bf16* dst; int n;
  if      (sel == 0) { src = x;  dst = xb;  n = B_ * S_ * D_; }
  else if (sel == 1) { src = wq; dst = wqb; n = D_ * D_; }
  else if (sel == 2) { src = wk; dst = wkb; n = D_ * D_; }
  else if (sel == 3) { src = wv; dst = wvb; n = D_ * D_; }
  else               { src = wo; dst = wob; n = D_ * D_; }
  for (int i = blockIdx.x * 256 + threadIdx.x; i * 4 < n; i += gridDim.x * 256) {
    const float4 v = *(const float4*)(src + (size_t)i * 4);
    bf16x4 o;
    o[0] = (__bf16)v.x; o[1] = (__bf16)v.y; o[2] = (__bf16)v.z; o[3] = (__bf16)v.w;
    *(bf16x4*)(dst + (size_t)i * 4) = o;
  }
}

// ---------------- m97-style GEMM body with pluggable store ----------------
template <typename F>
__device__ __forceinline__ void gemm97_body(const __bf16* __restrict__ A,
                                            const __bf16* __restrict__ Bm,
                                            const int m0, const int n0,
                                            const int K, F&& store) {
  __shared__ __align__(16) __bf16 As[128 * 64];
  __shared__ __align__(16) __bf16 Bs[128 * 64];
  const int tid  = threadIdx.x, lane = tid & 63, wave = tid >> 6;
  const int l15  = lane & 15,   quad = lane >> 4;
  const int wr   = wave >> 1,   wc   = wave & 1;
  const int ebase = wave * 2048 + lane * 8;

  f32x4 acc[4][4] = {};
  for (int k0 = 0; k0 < K; k0 += 64) {
#pragma unroll
    for (int i = 0; i < 4; ++i) {
      const int e = ebase + i * 512;
      const int row = e >> 6, col = e & 63;
      async16(A  + (size_t)(m0 + row) * K + k0 + col, As + (wave * 4 + i) * 512);
      async16(Bm + (size_t)(n0 + row) * K + k0 + col, Bs + (wave * 4 + i) * 512);
    }
    __syncthreads();
#pragma unroll
    for (int kk = 0; kk < 2; ++kk) {
      bf16x8 af[4], bfv[4];
#pragma unroll
      for (int rt = 0; rt < 4; ++rt)
        af[rt] = *(const bf16x8*)(As + (wr * 64 + rt * 16 + l15) * 64 + kk * 32 + quad * 8);
#pragma unroll
      for (int ct = 0; ct < 4; ++ct)
        bfv[ct] = *(const bf16x8*)(Bs + (wc * 64 + ct * 16 + l15) * 64 + kk * 32 + quad * 8);
#pragma unroll
      for (int rt = 0; rt < 4; ++rt)
#pragma unroll
        for (int ct = 0; ct < 4; ++ct)
          acc[rt][ct] = __builtin_amdgcn_mfma_f32_16x16x32_bf16(af[rt], bfv[ct], acc[rt][ct], 0, 0, 0);
    }
    __syncthreads();
  }
#pragma unroll
  for (int rt = 0; rt < 4; ++rt)
#pragma unroll
    for (int ct = 0; ct < 4; ++ct)
#pragma unroll
      for (int r = 0; r < 4; ++r) {
        const int row = m0 + wr * 64 + rt * 16 + quad * 4 + r;
        const int col = n0 + wc * 64 + ct * 16 + l15;
        store(row, col, acc[rt][ct][r]);
      }
}

// Q row-major; K,V fragment-major for attn:
// Kf[bh][T][(kti*2+kk)*64 + l15k + quadk*16][j]  (A-operand map)
//   s = T*128+kti*16+l15k, d = h*64+kk*32+quadk*8+j
// Vf[bh][T][(nt*4+kb)*64 + quadv*16 + l15v][j]   (B-operand map)
//   s = T*128+kb*32+quadv*8+j, d = h*64+nt*16+l15v
__global__ __launch_bounds__(256) void qkv_gemm(const __bf16* __restrict__ xb,
                                                const __bf16* __restrict__ wq,
                                                const __bf16* __restrict__ wk,
                                                const __bf16* __restrict__ wv,
                                                __bf16* __restrict__ qb,
                                                __bf16* __restrict__ kfb,
                                                __bf16* __restrict__ vfb) {
  const int sel = blockIdx.x >> 3;
  const int m0 = blockIdx.y * 128, n0 = (blockIdx.x & 7) * 128;
  if (sel == 0) {
    gemm97_body(xb, wq, m0, n0, D_, [&](int row, int col, float v) {
      qb[(size_t)row * D_ + col] = (__bf16)v;
    });
  } else if (sel == 1) {
    gemm97_body(xb, wk, m0, n0, D_, [&](int row, int col, float v) {
      const int b = row >> 11, ss = row & 2047;
      const int T = ss >> 7, kti = (ss >> 4) & 7, l15k = ss & 15;
      const int h = col >> 6, dd = col & 63;
      const int kk = dd >> 5, quadk = (dd >> 3) & 3, j = dd & 7;
      kfb[((size_t)((b * 16 + h) * 16 + T)) * 8192 +
          ((kti * 2 + kk) * 64 + l15k + quadk * 16) * 8 + j] = (__bf16)v;
    });
  } else {
    gemm97_body(xb, wv, m0, n0, D_, [&](int row, int col, float v) {
      const int b = row >> 11, ss = row & 2047;
      const int T = ss >> 7, s = ss & 127;
      const int kb = s >> 5, quadv = (s >> 3) & 3, j = s & 7;
      const int h = col >> 6, dd = col & 63;
      const int nt = dd >> 4, l15v = dd & 15;
      vfb[((size_t)((b * 16 + h) * 16 + T)) * 8192 +
          ((nt * 4 + kb) * 64 + quadv * 16 + l15v) * 8 + j] = (__bf16)v;
    });
  }
}

__global__ __launch_bounds__(256) void o_gemm(const __bf16* __restrict__ cb,
                                              const __bf16* __restrict__ wo,
                                              float* __restrict__ out) {
  gemm97_body(cb, wo, blockIdx.y * 128, blockIdx.x * 128, D_,
              [&](int row, int col, float v) { out[(size_t)row * D_ + col] = v; });
}

// ---------------- flash attention: coalesced frag-major K/V ----------------
// Block: 128 q of one (b,h); 4 waves x 32 q. Every in-loop K/V fragment load is
// one coalesced 1KB wave load (lane-indexed). LDS = ps only; write->read
// barrier-bracketed (R3). NO launch_bounds min-waves (R5 spill lesson).
__global__ __launch_bounds__(256) void attn6(const __bf16* __restrict__ Q,
                                             const __bf16* __restrict__ Kf,
                                             const __bf16* __restrict__ Vf,
                                             const float* __restrict__ mask,
                                             __bf16* __restrict__ O) {
  constexpr int LPS = 136;
  __shared__ __align__(16) __bf16 ps[128 * LPS];

  const int tid  = threadIdx.x, lane = tid & 63, wave = tid >> 6;
  const int l15  = lane & 15,   quad = lane >> 4;
  const int b = blockIdx.z, h = blockIdx.y, q0 = blockIdx.x * 128;
  const int bh = b * H_ + h;
  const size_t base = (size_t)b * S_ * D_ + h * HD_;
  const __bf16* kfh = Kf + (size_t)bh * (16 * 8192);
  const __bf16* vfh = Vf + (size_t)bh * (16 * 8192);
  const float* mrow = mask + (size_t)b * S_;
  const int qw = q0 + wave * 32;
  const float L2E = 1.442695041f;

  // Q fragments (B-operand; once per block)
  bf16x8 qf[2][2];
#pragma unroll
  for (int t = 0; t < 2; ++t)
#pragma unroll
    for (int kb = 0; kb < 2; ++kb)
      qf[t][kb] = *(const bf16x8*)(Q + base + (size_t)(qw + t * 16 + l15) * D_ + kb * 32 + quad * 8);

  float m_run[2] = {-1e30f, -1e30f}, l_run[2] = {0.f, 0.f};
  f32x4 oacc[2][4] = {};

  for (int T = 0; T < 16; ++T) {
    __syncthreads();  // prev iter's ps reads done before this iter's writes
    const __bf16* kft = kfh + (size_t)T * 8192;
    const __bf16* vft = vfh + (size_t)T * 8192;
    const int t0 = T * 128;

    // ---- S^T: D[m=key][n=q]; A-frags = coalesced lane-indexed loads ----
    f32x4 sacc[8][2] = {};
#pragma unroll
    for (int kti = 0; kti < 8; ++kti) {
      const bf16x8 a0 = *(const bf16x8*)(kft + (kti * 2 + 0) * 512 + lane * 8);
      const bf16x8 a1 = *(const bf16x8*)(kft + (kti * 2 + 1) * 512 + lane * 8);
#pragma unroll
      for (int t = 0; t < 2; ++t) {
        sacc[kti][t] = __builtin_amdgcn_mfma_f32_16x16x32_bf16(a0, qf[t][0], sacc[kti][t], 0, 0, 0);
        sacc[kti][t] = __builtin_amdgcn_mfma_f32_16x16x32_bf16(a1, qf[t][1], sacc[kti][t], 0, 0, 0);
      }
    }
    // scale + additive mask
#pragma unroll
    for (int kti = 0; kti < 8; ++kti) {
      const f32x4 mv = *(const f32x4*)(mrow + t0 + kti * 16 + quad * 4);
#pragma unroll
      for (int t = 0; t < 2; ++t)
#pragma unroll
        for (int r = 0; r < 4; ++r)
          sacc[kti][t][r] = fmaf(sacc[kti][t][r], 0.125f, mv[r]);
    }
    // online softmax
    float mnew[2], alpha[2], tsum[2], ml2[2];
#pragma unroll
    for (int t = 0; t < 2; ++t) {
      float tm = -1e30f;
#pragma unroll
      for (int kti = 0; kti < 8; ++kti)
#pragma unroll
        for (int r = 0; r < 4; ++r) tm = fmaxf(tm, sacc[kti][t][r]);
      tm = fmaxf(tm, __shfl_xor(tm, 16));
      tm = fmaxf(tm, __shfl_xor(tm, 32));
      mnew[t]  = fmaxf(m_run[t], tm);
      alpha[t] = __builtin_amdgcn_exp2f((m_run[t] - mnew[t]) * L2E);
      m_run[t] = mnew[t];
      ml2[t]   = mnew[t] * L2E;
      tsum[t]  = 0.f;
    }
    // P = exp2(...), write P[q][key]
#pragma unroll
    for (int t = 0; t < 2; ++t) {
      __bf16* pr = ps + (size_t)(wave * 32 + t * 16 + l15) * LPS + quad * 4;
#pragma unroll
      for (int kti = 0; kti < 8; ++kti) {
        bf16x4 pv;
#pragma unroll
        for (int r = 0; r < 4; ++r) {
          const float p = __builtin_amdgcn_exp2f(fmaf(sacc[kti][t][r], L2E, -ml2[t]));
          tsum[t] += p;
          pv[r] = (__bf16)p;
        }
        *(bf16x4*)(pr + kti * 16) = pv;
      }
    }
#pragma unroll
    for (int t = 0; t < 2; ++t) {
      float ts = tsum[t];
      ts += __shfl_xor(ts, 16);
      ts += __shfl_xor(ts, 32);
      l_run[t] = l_run[t] * alpha[t] + ts;
#pragma unroll
      for (int r = 0; r < 4; ++r) {
        const float aR = __shfl(alpha[t], quad * 4 + r);
#pragma unroll
        for (int nt = 0; nt < 4; ++nt) oacc[t][nt][r] *= aR;
      }
    }
    __syncthreads();  // ps writes before A-layout reads
    // ---- O += P·V; B-frags = coalesced lane-indexed loads ----
#pragma unroll
    for (int kb = 0; kb < 4; ++kb) {
      bf16x8 pa[2];
#pragma unroll
      for (int t = 0; t < 2; ++t)
        pa[t] = *(const bf16x8*)(ps + (size_t)(wave * 32 + t * 16 + l15) * LPS + kb * 32 + quad * 8);
#pragma unroll
      for (int nt = 0; nt < 4; ++nt) {
        const bf16x8 vf = *(const bf16x8*)(vft + (nt * 4 + kb) * 512 + lane * 8);
#pragma unroll
        for (int t = 0; t < 2; ++t)
          oacc[t][nt] = __builtin_amdgcn_mfma_f32_16x16x32_bf16(pa[t], vf, oacc[t][nt], 0, 0, 0);
      }
    }
  }
  // epilogue
#pragma unroll
  for (int t = 0; t < 2; ++t)
#pragma unroll
    for (int r = 0; r < 4; ++r) {
      const float lR  = __shfl(l_run[t], quad * 4 + r);
      const float inv = 1.0f / lR;
      const int row = qw + t * 16 + quad * 4 + r;
#pragma unroll
      for (int nt = 0; nt < 4; ++nt)
        O[base + (size_t)row * D_ + nt * 16 + l15] = (__bf16)(oacc[t][nt][r] * inv);
    }
}

extern "C" void kernel_launch(void* const* d_in, const int* in_sizes, int n_in,
                              void* d_out, int out_size, void* d_ws, size_t ws_size,
                              hipStream_t stream) {
  const float* x    = (const float*)d_in[0];
  const float* mask = (const float*)d_in[1];
  const float* Wq   = (const float*)d_in[2];
  const float* Wk   = (const float*)d_in[3];
  const float* Wv   = (const float*)d_in[4];
  const float* Wo   = (const float*)d_in[5];

  char* ws = (char*)d_ws;
  const size_t MB = 1ull << 20;
  __bf16* xb  = (__bf16*)(ws);             // 8 MB; reused as cb after qkv_gemm
  __bf16* wqb = (__bf16*)(ws + 8 * MB);
  __bf16* wkb = (__bf16*)(ws + 10 * MB);
  __bf16* wvb = (__bf16*)(ws + 12 * MB);
  __bf16* wob = (__bf16*)(ws + 14 * MB);
  __bf16* qb  = (__bf16*)(ws + 16 * MB);   // 8 MB row-major Q
  __bf16* kfb = (__bf16*)(ws + 24 * MB);   // 8 MB fragment-major K
  __bf16* vfb = (__bf16*)(ws + 32 * MB);   // 8 MB fragment-major V
  __bf16* cb  = xb;  // x fully consumed by qkv_gemm before attn writes ctx

  cvt_all<<<dim3(1024, 5), 256, 0, stream>>>(x, Wq, Wk, Wv, Wo, xb, wqb, wkb, wvb, wob);
  qkv_gemm<<<dim3(24, 32), 256, 0, stream>>>(xb, wqb, wkb, wvb, qb, kfb, vfb);
  attn6<<<dim3(S_ / 128, H_, B_), 256, 0, stream>>>(qb, kfb, vfb, mask, cb);
  o_gemm<<<dim3(8, 32), 256, 0, stream>>>(cb, wob, (float*)d_out);
}

// Round 7
// 281.031 us; speedup vs baseline: 1.2615x; 1.0062x over previous
//
#include <hip/hip_runtime.h>
#include <hip/hip_bf16.h>
#include <cstdint>
#include <cstddef>

// MHA B=2,S=2048,D=1024,H=16,HD=64.
// cvt -> QKV GEMM (m97 staging; K,V packed fragment-major via LDS in epilogue,
// coalesced stores) -> flash attn (64q blocks, coalesced global K/V frags,
// ping-pong P in LDS, one barrier/iter) -> O GEMM.
//
// R3: cross-lane LDS write->read must be barrier-bracketed.
// R4: direct-global MFMA fragments need a CONTIGUOUS lane->address map.
// R5: no launch_bounds min-waves on register-heavy kernels (spill).
// R6: scatter 2B global stores in epilogue are slower than LDS-pack+coalesced
//     copy; attn occupancy was grid-capped at 2 blocks/CU.

#define B_  2
#define S_  2048
#define D_  1024
#define H_  16
#define HD_ 64

typedef __bf16 bf16x8 __attribute__((ext_vector_type(8)));
typedef __bf16 bf16x4 __attribute__((ext_vector_type(4)));
typedef float  f32x4  __attribute__((ext_vector_type(4)));

__device__ __forceinline__ void async16(const __bf16* g, const __bf16* l) {
  __builtin_amdgcn_global_load_lds(
      (const __attribute__((address_space(1))) void*)(uintptr_t)g,
      (__attribute__((address_space(3))) void*)(uint32_t)(uintptr_t)l,
      16, 0, 0);
}

// ---------------- fp32 -> bf16 convert (x + 4 weights) ----------------
__global__ __launch_bounds__(256) void cvt_all(const float* __restrict__ x,
    const float* __restrict__ wq, const float* __restrict__ wk,
    const float* __restrict__ wv, const float* __restrict__ wo,
    __bf16* __restrict__ xb, __bf16* __restrict__ wqb, __bf16* __restrict__ wkb,
    __bf16* __restrict__ wvb, __bf16* __restrict__ wob) {
  const int sel = blockIdx.y;
  const float* src; __bf16* dst; int n;
  if      (sel == 0) { src = x;  dst = xb;  n = B_ * S_ * D_; }
  else if (sel == 1) { src = wq; dst = wqb; n = D_ * D_; }
  else if (sel == 2) { src = wk; dst = wkb; n = D_ * D_; }
  else if (sel == 3) { src = wv; dst = wvb; n = D_ * D_; }
  else               { src = wo; dst = wob; n = D_ * D_; }
  for (int i = blockIdx.x * 256 + threadIdx.x; i * 4 < n; i += gridDim.x * 256) {
    const float4 v = *(const float4*)(src + (size_t)i * 4);
    bf16x4 o;
    o[0] = (__bf16)v.x; o[1] = (__bf16)v.y; o[2] = (__bf16)v.z; o[3] = (__bf16)v.w;
    *(bf16x4*)(dst + (size_t)i * 4) = o;
  }
}

// ---------------- m97 GEMM core: acc = A[M][K] * B[N][K]^T tile ----------------
// smem: 16384 bf16 (32 KB). As = smem, Bs = smem+8192. Ends with __syncthreads()
// so caller may reuse smem as epilogue scratch.
__device__ __forceinline__ void gemm97_core(const __bf16* __restrict__ A,
                                            const __bf16* __restrict__ Bm,
                                            const int m0, const int n0, const int K,
                                            __bf16* smem, f32x4 acc[4][4]) {
  __bf16* As = smem;
  __bf16* Bs = smem + 8192;
  const int tid  = threadIdx.x, lane = tid & 63, wave = tid >> 6;
  const int l15  = lane & 15,   quad = lane >> 4;
  const int wr   = wave >> 1,   wc   = wave & 1;
  const int ebase = wave * 2048 + lane * 8;

  for (int k0 = 0; k0 < K; k0 += 64) {
#pragma unroll
    for (int i = 0; i < 4; ++i) {
      const int e = ebase + i * 512;
      const int row = e >> 6, col = e & 63;
      async16(A  + (size_t)(m0 + row) * K + k0 + col, As + (wave * 4 + i) * 512);
      async16(Bm + (size_t)(n0 + row) * K + k0 + col, Bs + (wave * 4 + i) * 512);
    }
    __syncthreads();
#pragma unroll
    for (int kk = 0; kk < 2; ++kk) {
      bf16x8 af[4], bfv[4];
#pragma unroll
      for (int rt = 0; rt < 4; ++rt)
        af[rt] = *(const bf16x8*)(As + (wr * 64 + rt * 16 + l15) * 64 + kk * 32 + quad * 8);
#pragma unroll
      for (int ct = 0; ct < 4; ++ct)
        bfv[ct] = *(const bf16x8*)(Bs + (wc * 64 + ct * 16 + l15) * 64 + kk * 32 + quad * 8);
#pragma unroll
      for (int rt = 0; rt < 4; ++rt)
#pragma unroll
        for (int ct = 0; ct < 4; ++ct)
          acc[rt][ct] = __builtin_amdgcn_mfma_f32_16x16x32_bf16(af[rt], bfv[ct], acc[rt][ct], 0, 0, 0);
    }
    __syncthreads();
  }
}

// Fragment-major layouts (8 KB per (bh,T) block):
// Kf[bh][T][(kti*2+kk)*64 + l15k + quadk*16][j]: s=T*128+kti*16+l15k, d=h*64+kk*32+quadk*8+j
// Vf[bh][T][(nt*4+kb)*64 + quadv*16 + l15v][j]:  s=T*128+kb*32+quadv*8+j, d=h*64+nt*16+l15v
__global__ __launch_bounds__(256) void qkv_gemm(const __bf16* __restrict__ xb,
                                                const __bf16* __restrict__ wq,
                                                const __bf16* __restrict__ wk,
                                                const __bf16* __restrict__ wv,
                                                __bf16* __restrict__ qb,
                                                __bf16* __restrict__ kfb,
                                                __bf16* __restrict__ vfb) {
  __shared__ __align__(16) __bf16 smem[16384];
  const int sel = blockIdx.x >> 3;
  const int m0 = blockIdx.y * 128, n0 = (blockIdx.x & 7) * 128;
  const int tid  = threadIdx.x, lane = tid & 63, wave = tid >> 6;
  const int l15  = lane & 15,   quad = lane >> 4;
  const int wr   = wave >> 1,   wc   = wave & 1;

  f32x4 acc[4][4] = {};
  const __bf16* Bm = (sel == 0) ? wq : (sel == 1) ? wk : wv;
  gemm97_core(xb, Bm, m0, n0, D_, smem, acc);

  if (sel == 0) {
    // Q row-major (read once per attn block; divergence there is negligible)
#pragma unroll
    for (int rt = 0; rt < 4; ++rt)
#pragma unroll
      for (int ct = 0; ct < 4; ++ct)
#pragma unroll
        for (int r = 0; r < 4; ++r) {
          const int row = m0 + wr * 64 + rt * 16 + quad * 4 + r;
          const int col = n0 + wc * 64 + ct * 16 + l15;
          qb[(size_t)row * D_ + col] = (__bf16)acc[rt][ct][r];
        }
    return;
  }

  // K/V: scatter acc -> LDS in fragment order, then coalesced linear copy.
#pragma unroll
  for (int rt = 0; rt < 4; ++rt)
#pragma unroll
    for (int ct = 0; ct < 4; ++ct)
#pragma unroll
      for (int r = 0; r < 4; ++r) {
        const int lr = wr * 64 + rt * 16 + quad * 4 + r;   // tile-local row (s)
        const int lc = wc * 64 + ct * 16 + l15;            // tile-local col (d)
        const int hl = lc >> 6, dd = lc & 63;
        int off;
        if (sel == 1) {  // K: A-operand map
          const int kti = (lr >> 4) & 7, l15k = lr & 15;
          const int kk = dd >> 5, quadk = (dd >> 3) & 3, j = dd & 7;
          off = ((kti * 2 + kk) * 64 + l15k + quadk * 16) * 8 + j;
        } else {         // V: B-operand map
          const int kb = lr >> 5, quadv = (lr >> 3) & 3, jv = lr & 7;
          const int nt = dd >> 4, l15v = dd & 15;
          off = ((nt * 4 + kb) * 64 + quadv * 16 + l15v) * 8 + jv;
        }
        smem[hl * 8192 + off] = (__bf16)acc[rt][ct][r];
      }
  __syncthreads();

  __bf16* dstb = (sel == 1) ? kfb : vfb;
  const int b = m0 >> 11, T = (m0 & 2047) >> 7, h0 = n0 >> 6;  // tile = heads h0,h0+1
  const size_t base0 = ((size_t)(b * 16 + h0) * 16 + T) * 8192;
#pragma unroll
  for (int i = 0; i < 8; ++i) {
    const int c = i * 256 + tid;       // 16B chunk index, 0..2047
    const int E = c * 8;               // element offset in smem
    const int hl = E >> 13;            // 0/1 -> head
    const size_t dst = base0 + (size_t)hl * (16 * 8192) + (E & 8191);
    *(bf16x8*)(dstb + dst) = *(const bf16x8*)(smem + E);
  }
}

__global__ __launch_bounds__(256) void o_gemm(const __bf16* __restrict__ cb,
                                              const __bf16* __restrict__ wo,
                                              float* __restrict__ out) {
  __shared__ __align__(16) __bf16 smem[16384];
  const int tid  = threadIdx.x, lane = tid & 63, wave = tid >> 6;
  const int l15  = lane & 15,   quad = lane >> 4;
  const int wr   = wave >> 1,   wc   = wave & 1;
  const int m0 = blockIdx.y * 128, n0 = blockIdx.x * 128;
  f32x4 acc[4][4] = {};
  gemm97_core(cb, wo, m0, n0, D_, smem, acc);
#pragma unroll
  for (int rt = 0; rt < 4; ++rt)
#pragma unroll
    for (int ct = 0; ct < 4; ++ct)
#pragma unroll
      for (int r = 0; r < 4; ++r) {
        const int row = m0 + wr * 64 + rt * 16 + quad * 4 + r;
        const int col = n0 + wc * 64 + ct * 16 + l15;
        out[(size_t)row * D_ + col] = acc[rt][ct][r];
      }
}

// ---------------- flash attention: 64q blocks, ping-pong P ----------------
// Grid (32,16,2)=1024 blocks -> 4 blocks/CU. Wave owns 16 q. One barrier/iter:
// iter T reads ps[T&1] after the barrier; iter T+2 rewrites ps[T&1] after
// iter T+1's barrier, which orders iter T's reads first (R3-safe).
__global__ __launch_bounds__(256) void attn7(const __bf16* __restrict__ Q,
                                             const __bf16* __restrict__ Kf,
                                             const __bf16* __restrict__ Vf,
                                             const float* __restrict__ mask,
                                             __bf16* __restrict__ O) {
  constexpr int LPS = 136;
  __shared__ __align__(16) __bf16 ps[2][64 * LPS];  // 34.8 KB

  const int tid  = threadIdx.x, lane = tid & 63, wave = tid >> 6;
  const int l15  = lane & 15,   quad = lane >> 4;
  const int b = blockIdx.z, h = blockIdx.y, q0 = blockIdx.x * 64;
  const int bh = b * H_ + h;
  const size_t base = (size_t)b * S_ * D_ + h * HD_;
  const __bf16* kfh = Kf + (size_t)bh * (16 * 8192);
  const __bf16* vfh = Vf + (size_t)bh * (16 * 8192);
  const float* mrow = mask + (size_t)b * S_;
  const int qw = q0 + wave * 16;
  const float L2E = 1.442695041f;

  // Q fragments (B-operand; once per block)
  bf16x8 qf[2];
#pragma unroll
  for (int kb = 0; kb < 2; ++kb)
    qf[kb] = *(const bf16x8*)(Q + base + (size_t)(qw + l15) * D_ + kb * 32 + quad * 8);

  float m_run = -1e30f, l_run = 0.f;
  f32x4 oacc[4] = {};

  for (int T = 0; T < 16; ++T) {
    const __bf16* kft = kfh + (size_t)T * 8192;
    const __bf16* vft = vfh + (size_t)T * 8192;
    __bf16* psb = ps[T & 1];
    const int t0 = T * 128;

    // ---- S^T: D[m=key][n=q]; coalesced lane-indexed A-frag loads ----
    f32x4 sacc[8] = {};
#pragma unroll
    for (int kti = 0; kti < 8; ++kti) {
      const bf16x8 a0 = *(const bf16x8*)(kft + (kti * 2 + 0) * 512 + lane * 8);
      const bf16x8 a1 = *(const bf16x8*)(kft + (kti * 2 + 1) * 512 + lane * 8);
      sacc[kti] = __builtin_amdgcn_mfma_f32_16x16x32_bf16(a0, qf[0], sacc[kti], 0, 0, 0);
      sacc[kti] = __builtin_amdgcn_mfma_f32_16x16x32_bf16(a1, qf[1], sacc[kti], 0, 0, 0);
    }
    // scale + additive mask (per-key)
#pragma unroll
    for (int kti = 0; kti < 8; ++kti) {
      const f32x4 mv = *(const f32x4*)(mrow + t0 + kti * 16 + quad * 4);
#pragma unroll
      for (int r = 0; r < 4; ++r)
        sacc[kti][r] = fmaf(sacc[kti][r], 0.125f, mv[r]);
    }
    // online softmax (per-lane over 32 keys, then quad hops)
    float tm = -1e30f;
#pragma unroll
    for (int kti = 0; kti < 8; ++kti)
#pragma unroll
      for (int r = 0; r < 4; ++r) tm = fmaxf(tm, sacc[kti][r]);
    tm = fmaxf(tm, __shfl_xor(tm, 16));
    tm = fmaxf(tm, __shfl_xor(tm, 32));
    const float mnew  = fmaxf(m_run, tm);
    const float alpha = __builtin_amdgcn_exp2f((m_run - mnew) * L2E);
    m_run = mnew;
    const float ml2 = mnew * L2E;
    float tsum = 0.f;

    // P = exp2(...), write P[q][key] into ping-pong buffer
    {
      __bf16* pr = psb + (wave * 16 + l15) * LPS + quad * 4;
#pragma unroll
      for (int kti = 0; kti < 8; ++kti) {
        bf16x4 pv;
#pragma unroll
        for (int r = 0; r < 4; ++r) {
          const float p = __builtin_amdgcn_exp2f(fmaf(sacc[kti][r], L2E, -ml2));
          tsum += p;
          pv[r] = (__bf16)p;
        }
        *(bf16x4*)(pr + kti * 16) = pv;
      }
    }
    tsum += __shfl_xor(tsum, 16);
    tsum += __shfl_xor(tsum, 32);
    l_run = l_run * alpha + tsum;
#pragma unroll
    for (int r = 0; r < 4; ++r) {
      const float aR = __shfl(alpha, quad * 4 + r);
#pragma unroll
      for (int nt = 0; nt < 4; ++nt) oacc[nt][r] *= aR;
    }

    __syncthreads();  // ps writes visible before A-layout reads (one barrier/iter)

    // ---- O += P·V; coalesced lane-indexed B-frag loads ----
#pragma unroll
    for (int kb = 0; kb < 4; ++kb) {
      const bf16x8 pa = *(const bf16x8*)(psb + (wave * 16 + l15) * LPS + kb * 32 + quad * 8);
#pragma unroll
      for (int nt = 0; nt < 4; ++nt) {
        const bf16x8 vf = *(const bf16x8*)(vft + (nt * 4 + kb) * 512 + lane * 8);
        oacc[nt] = __builtin_amdgcn_mfma_f32_16x16x32_bf16(pa, vf, oacc[nt], 0, 0, 0);
      }
    }
  }
  // epilogue
#pragma unroll
  for (int r = 0; r < 4; ++r) {
    const float lR  = __shfl(l_run, quad * 4 + r);
    const float inv = 1.0f / lR;
    const int row = qw + quad * 4 + r;
#pragma unroll
    for (int nt = 0; nt < 4; ++nt)
      O[base + (size_t)row * D_ + nt * 16 + l15] = (__bf16)(oacc[nt][r] * inv);
  }
}

extern "C" void kernel_launch(void* const* d_in, const int* in_sizes, int n_in,
                              void* d_out, int out_size, void* d_ws, size_t ws_size,
                              hipStream_t stream) {
  const float* x    = (const float*)d_in[0];
  const float* mask = (const float*)d_in[1];
  const float* Wq   = (const float*)d_in[2];
  const float* Wk   = (const float*)d_in[3];
  const float* Wv   = (const float*)d_in[4];
  const float* Wo   = (const float*)d_in[5];

  char* ws = (char*)d_ws;
  const size_t MB = 1ull << 20;
  __bf16* xb  = (__bf16*)(ws);             // 8 MB; reused as cb after qkv_gemm
  __bf16* wqb = (__bf16*)(ws + 8 * MB);
  __bf16* wkb = (__bf16*)(ws + 10 * MB);
  __bf16* wvb = (__bf16*)(ws + 12 * MB);
  __bf16* wob = (__bf16*)(ws + 14 * MB);
  __bf16* qb  = (__bf16*)(ws + 16 * MB);   // 8 MB row-major Q
  __bf16* kfb = (__bf16*)(ws + 24 * MB);   // 8 MB fragment-major K
  __bf16* vfb = (__bf16*)(ws + 32 * MB);   // 8 MB fragment-major V
  __bf16* cb  = xb;  // x fully consumed by qkv_gemm before attn writes ctx

  cvt_all<<<dim3(1024, 5), 256, 0, stream>>>(x, Wq, Wk, Wv, Wo, xb, wqb, wkb, wvb, wob);
  qkv_gemm<<<dim3(24, 32), 256, 0, stream>>>(xb, wqb, wkb, wvb, qb, kfb, vfb);
  attn7<<<dim3(S_ / 64, H_, B_), 256, 0, stream>>>(qb, kfb, vfb, mask, cb);
  o_gemm<<<dim3(8, 32), 256, 0, stream>>>(cb, wob, (float*)d_out);
}